// Round 5
// baseline (3351.792 us; speedup 1.0000x reference)
//
#include <hip/hip_runtime.h>
#include <hip/hip_bf16.h>
#include <math.h>

// Problem dims
#define B_  32
#define T_  512
#define D_  128
#define N_  1024
#define NOISE_ 0.001f

#define NWORK 32          // recurrence blocks; each owns N_/NWORK = 32 columns
#define CPB   32          // columns per block

typedef __attribute__((ext_vector_type(8))) short  bf16x8;
typedef __attribute__((ext_vector_type(4))) float  f32x4;

static __device__ __forceinline__ unsigned short f2bf_rn(float f) {
    unsigned int u = __builtin_bit_cast(unsigned int, f);
    unsigned int r = (u + 0x7FFFu + ((u >> 16) & 1u)) >> 16;
    return (unsigned short)r;
}
static __device__ __forceinline__ float bf2f(unsigned short h) {
    return __builtin_bit_cast(float, (unsigned int)h << 16);
}

// ---------------------------------------------------------------------------
// Kernel A: xin = (x @ w_input) * scale, written INTO d_out at [b][t][n].
// (unchanged, verified)
// ---------------------------------------------------------------------------
__global__ __launch_bounds__(256) void xin_gemm(
    const float* __restrict__ x, const float* __restrict__ w_in,
    const float* __restrict__ scale_p, float* __restrict__ out) {
  __shared__ float As[64 * 132];
  __shared__ float Bs[128 * 68];
  const int tid = threadIdx.x;
  const int bm = blockIdx.x;       // 0..255
  const int bn = blockIdx.y;       // 0..15

  {
    const f32x4* xg = (const f32x4*)(x + (size_t)bm * 64 * 128);
#pragma unroll
    for (int i = 0; i < 8; ++i) {
      int idx = tid + i * 256;
      int r = idx >> 5, c4 = idx & 31;
      f32x4 v = xg[idx];
      float* dst = &As[r * 132 + c4 * 4];
      dst[0] = v.x; dst[1] = v.y; dst[2] = v.z; dst[3] = v.w;
    }
  }
  {
#pragma unroll
    for (int i = 0; i < 8; ++i) {
      int idx = tid + i * 256;
      int r = idx >> 4, c4 = idx & 15;
      f32x4 v = *(const f32x4*)(w_in + (size_t)r * N_ + bn * 64 + c4 * 4);
      float* dst = &Bs[r * 68 + c4 * 4];
      dst[0] = v.x; dst[1] = v.y; dst[2] = v.z; dst[3] = v.w;
    }
  }
  __syncthreads();

  const int tx = tid & 15, ty = tid >> 4;
  float acc[4][4] = {};
  for (int k = 0; k < 128; ++k) {
    float a0 = As[(ty * 4 + 0) * 132 + k];
    float a1 = As[(ty * 4 + 1) * 132 + k];
    float a2 = As[(ty * 4 + 2) * 132 + k];
    float a3 = As[(ty * 4 + 3) * 132 + k];
    f32x4 bv = *(const f32x4*)&Bs[k * 68 + tx * 4];
#pragma unroll
    for (int j = 0; j < 4; ++j) {
      acc[0][j] += a0 * bv[j];
      acc[1][j] += a1 * bv[j];
      acc[2][j] += a2 * bv[j];
      acc[3][j] += a3 * bv[j];
    }
  }
  const float s = scale_p[0];
#pragma unroll
  for (int i = 0; i < 4; ++i) {
    int row = bm * 64 + ty * 4 + i;
    if ((row & 511) == 0) continue;
    f32x4 o;
    o.x = acc[i][0] * s; o.y = acc[i][1] * s;
    o.z = acc[i][2] * s; o.w = acc[i][3] * s;
    *(f32x4*)(out + (size_t)row * N_ + bn * 64 + tx * 4) = o;
  }
}

// ---------------------------------------------------------------------------
// Kernel B: out[:,0,:] = step0 ; states0 -> compensated bf16 ping buffer 0 ;
// zero per-block flags. (unchanged, verified)
// ---------------------------------------------------------------------------
__global__ __launch_bounds__(256) void init_k(
    const float* __restrict__ states0, const float* __restrict__ step0,
    float* __restrict__ out, unsigned short* __restrict__ st_hi,
    unsigned short* __restrict__ st_lo, int* __restrict__ flags) {
  int i = blockIdx.x * 256 + threadIdx.x;
  if (i < B_ * N_) {
    int b = i >> 10, n = i & 1023;
    out[((size_t)b * T_ + 0) * N_ + n] = step0[i];
    float sv = states0[i];
    unsigned short h = f2bf_rn(sv);
    st_hi[i] = h;
    st_lo[i] = f2bf_rn(sv - bf2f(h));
  }
  if (i < 1024) flags[i] = 0;   // flags at 16-int (64 B) stride
}

// ---------------------------------------------------------------------------
// Kernel C: persistent recurrence. 32 blocks x 256 threads.
// VERIFIED baseline protocol exactly (system-scope __hip_atomic poll/publish,
// sc0 sc1 state-load asm, vmcnt(0) drains, two __syncthreads per step).
// grid == NWORK == 32: trivially co-resident, no election, no hwreg.
// vs baseline: CPB 16->32 (halves LLC state broadcast + tail width), W-slice
// fragments gathered ONE-TIME from global into registers (no W LDS at all ->
// LDS = 16.9 KB partials only), 4 independent acc chains, split
// vmcnt(16)/vmcnt(0), asm xin prefetch with a VALID 32-bit saddr offset.
// Per-output arithmetic bitwise identical to the verified kernel.
// ---------------------------------------------------------------------------
__global__ __launch_bounds__(256, 1) void esn_rec(
    const float* __restrict__ w_res, const float* __restrict__ rn,
    float* __restrict__ out, unsigned short* __restrict__ st_hi,
    unsigned short* __restrict__ st_lo, int* flags) {
  __shared__ float pLDS[4 * 32 * 33];   // 16896 B  [wave][row32][col32 pad33]

  const int tid = threadIdx.x;
  const int blk = blockIdx.x;           // 0..31, every block is a worker

  const int lane = tid & 63, wave = tid >> 6;
  const int quad = lane >> 4, lm = lane & 15;

  // ---- one-time: gather loop-invariant W fragments straight into registers.
  // B-fragment element j of (kk, col-tile ct) is w_res[k][c] with
  // k = wave*256 + kk*32 + quad*8 + j , c = blk*32 + ct*16 + lm.
  // Same f2bf_rn hi/lo split as the verified kernel -> identical MFMA inputs.
  bf16x8 BH[8][2], BL[8][2];
#pragma unroll
  for (int kk = 0; kk < 8; ++kk) {
#pragma unroll
    for (int ct = 0; ct < 2; ++ct) {
      const float* wp = w_res + (size_t)(wave * 256 + kk * 32 + quad * 8) * N_
                              + blk * CPB + ct * 16 + lm;
      bf16x8 hv, lv;
#pragma unroll
      for (int j = 0; j < 8; ++j) {
        float wv = wp[(size_t)j * N_];
        unsigned short h = f2bf_rn(wv);
        hv[j] = (short)h;
        lv[j] = (short)f2bf_rn(wv - bf2f(h));
      }
      BH[kk][ct] = hv;
      BL[kk][ct] = lv;
    }
  }

  // epilogue mapping: thread owns (row rm, cols cg..cg+3)
  const int rm = tid >> 3;               // 0..31
  const int cg = (tid & 7) * 4;          // 0,4,..,28
  const int colg = blk * CPB + cg;
  float4 nz = *(const float4*)&rn[(size_t)rm * N_ + colg];
  nz.x *= NOISE_; nz.y *= NOISE_; nz.z *= NOISE_; nz.w *= NOISE_;

  // byte voffsets for the wave's state fragments (rows lm and lm+16)
  const int vo0 = lm * 2048 + wave * 512 + quad * 16;
  const int vo1 = vo0 + 16 * 2048;
  // wave w needs k-slice [256w,256w+256) => producer blocks 8w..8w+7
  const int fidx = (wave * 8 + (lane & 7)) * 16;

  __syncthreads();

  for (int t = 1; t < T_; ++t) {
    const int pc = (t - 1) & 1, ncur = t & 1;

    // prefetch xin (own slot; written by xin_gemm, read+overwritten by us).
    // Pinned asm, VALID saddr form: single 32-bit VGPR byte offset + s-base.
    size_t o0 = ((size_t)rm * T_ + t) * N_ + colg;
    f32x4 xv;
    {
      int loff = (int)(o0 * 4);          // < 2^27 bytes, fits easily
      const char* ob = (const char*)out;
      asm volatile("global_load_dwordx4 %0, %1, %2"
                   : "=v"(xv) : "v"(loff), "s"(ob) : "memory");
    }

    // per-wave poll: verified baseline form (C atomic loads, SYSTEM scope)
    {
      const int need = t - 1;
      while (true) {
        int f = __hip_atomic_load(&flags[fidx], __ATOMIC_RELAXED,
                                  __HIP_MEMORY_SCOPE_SYSTEM);
        if (__all(f >= need)) break;
      }
    }

    // state fragment loads: verified sc0 sc1 form, all 32 in flight
    const char* baseH = (const char*)(st_hi + pc * (B_ * N_));
    const char* baseL = (const char*)(st_lo + pc * (B_ * N_));
    bf16x8 AH0[8], AH1[8], AL0[8], AL1[8];
#pragma unroll
    for (int kk = 0; kk < 8; ++kk) {
      int oa = vo0 + kk * 64, ob = vo1 + kk * 64;
      asm volatile("global_load_dwordx4 %0, %1, %2 sc0 sc1"
                   : "=v"(AH0[kk]) : "v"(oa), "s"(baseH) : "memory");
      asm volatile("global_load_dwordx4 %0, %1, %2 sc0 sc1"
                   : "=v"(AH1[kk]) : "v"(ob), "s"(baseH) : "memory");
      asm volatile("global_load_dwordx4 %0, %1, %2 sc0 sc1"
                   : "=v"(AL0[kk]) : "v"(oa), "s"(baseL) : "memory");
      asm volatile("global_load_dwordx4 %0, %1, %2 sc0 sc1"
                   : "=v"(AL1[kk]) : "v"(ob), "s"(baseL) : "memory");
    }

    f32x4 acc00 = {0.f, 0.f, 0.f, 0.f};   // rows 0-15,  col-tile 0
    f32x4 acc01 = {0.f, 0.f, 0.f, 0.f};   // rows 16-31, col-tile 0
    f32x4 acc10 = {0.f, 0.f, 0.f, 0.f};   // rows 0-15,  col-tile 1
    f32x4 acc11 = {0.f, 0.f, 0.f, 0.f};   // rows 16-31, col-tile 1

    // first half (kk 0..3 = oldest 16 state loads) ready at vmcnt(16);
    // xin prefetch was already drained by the poll's waits.
    asm volatile("s_waitcnt vmcnt(16)" ::: "memory");
    __builtin_amdgcn_sched_barrier(0);   // rule #18: no MFMA hoist past wait
#pragma unroll
    for (int kk = 0; kk < 4; ++kk) {
      acc00 = __builtin_amdgcn_mfma_f32_16x16x32_bf16(AH0[kk], BH[kk][0], acc00, 0, 0, 0);
      acc01 = __builtin_amdgcn_mfma_f32_16x16x32_bf16(AH1[kk], BH[kk][0], acc01, 0, 0, 0);
      acc10 = __builtin_amdgcn_mfma_f32_16x16x32_bf16(AH0[kk], BH[kk][1], acc10, 0, 0, 0);
      acc11 = __builtin_amdgcn_mfma_f32_16x16x32_bf16(AH1[kk], BH[kk][1], acc11, 0, 0, 0);
      acc00 = __builtin_amdgcn_mfma_f32_16x16x32_bf16(AL0[kk], BH[kk][0], acc00, 0, 0, 0);
      acc01 = __builtin_amdgcn_mfma_f32_16x16x32_bf16(AL1[kk], BH[kk][0], acc01, 0, 0, 0);
      acc10 = __builtin_amdgcn_mfma_f32_16x16x32_bf16(AL0[kk], BH[kk][1], acc10, 0, 0, 0);
      acc11 = __builtin_amdgcn_mfma_f32_16x16x32_bf16(AL1[kk], BH[kk][1], acc11, 0, 0, 0);
      acc00 = __builtin_amdgcn_mfma_f32_16x16x32_bf16(AH0[kk], BL[kk][0], acc00, 0, 0, 0);
      acc01 = __builtin_amdgcn_mfma_f32_16x16x32_bf16(AH1[kk], BL[kk][0], acc01, 0, 0, 0);
      acc10 = __builtin_amdgcn_mfma_f32_16x16x32_bf16(AH0[kk], BL[kk][1], acc10, 0, 0, 0);
      acc11 = __builtin_amdgcn_mfma_f32_16x16x32_bf16(AH1[kk], BL[kk][1], acc11, 0, 0, 0);
    }
    asm volatile("s_waitcnt vmcnt(0)" ::: "memory");
    __builtin_amdgcn_sched_barrier(0);
#pragma unroll
    for (int kk = 4; kk < 8; ++kk) {
      acc00 = __builtin_amdgcn_mfma_f32_16x16x32_bf16(AH0[kk], BH[kk][0], acc00, 0, 0, 0);
      acc01 = __builtin_amdgcn_mfma_f32_16x16x32_bf16(AH1[kk], BH[kk][0], acc01, 0, 0, 0);
      acc10 = __builtin_amdgcn_mfma_f32_16x16x32_bf16(AH0[kk], BH[kk][1], acc10, 0, 0, 0);
      acc11 = __builtin_amdgcn_mfma_f32_16x16x32_bf16(AH1[kk], BH[kk][1], acc11, 0, 0, 0);
      acc00 = __builtin_amdgcn_mfma_f32_16x16x32_bf16(AL0[kk], BH[kk][0], acc00, 0, 0, 0);
      acc01 = __builtin_amdgcn_mfma_f32_16x16x32_bf16(AL1[kk], BH[kk][0], acc01, 0, 0, 0);
      acc10 = __builtin_amdgcn_mfma_f32_16x16x32_bf16(AL0[kk], BH[kk][1], acc10, 0, 0, 0);
      acc11 = __builtin_amdgcn_mfma_f32_16x16x32_bf16(AL1[kk], BH[kk][1], acc11, 0, 0, 0);
      acc00 = __builtin_amdgcn_mfma_f32_16x16x32_bf16(AH0[kk], BL[kk][0], acc00, 0, 0, 0);
      acc01 = __builtin_amdgcn_mfma_f32_16x16x32_bf16(AH1[kk], BL[kk][0], acc01, 0, 0, 0);
      acc10 = __builtin_amdgcn_mfma_f32_16x16x32_bf16(AH0[kk], BL[kk][1], acc10, 0, 0, 0);
      acc11 = __builtin_amdgcn_mfma_f32_16x16x32_bf16(AH1[kk], BL[kk][1], acc11, 0, 0, 0);
    }

    // write K-partials: C frag layout row=quad*4+r, col=lm (per col-tile)
#pragma unroll
    for (int r = 0; r < 4; ++r) {
      pLDS[wave * 1056 + (quad * 4 + r) * 33 + lm]           = acc00[r];
      pLDS[wave * 1056 + (quad * 4 + r + 16) * 33 + lm]      = acc01[r];
      pLDS[wave * 1056 + (quad * 4 + r) * 33 + 16 + lm]      = acc10[r];
      pLDS[wave * 1056 + (quad * 4 + r + 16) * 33 + 16 + lm] = acc11[r];
    }
    __syncthreads();

    // reduce 4 K-partials for (rm, cg..cg+3)   (same order as verified kernel)
    float s0 = 0.f, s1 = 0.f, s2 = 0.f, s3 = 0.f;
#pragma unroll
    for (int w = 0; w < 4; ++w) {
      const float* p = &pLDS[w * 1056 + rm * 33 + cg];
      s0 += p[0]; s1 += p[1]; s2 += p[2]; s3 += p[3];
    }
    float v0 = tanhf(s0 + xv[0]) + nz.x;
    float v1 = tanhf(s1 + xv[1]) + nz.y;
    float v2 = tanhf(s2 + xv[2]) + nz.z;
    float v3 = tanhf(s3 + xv[3]) + nz.w;
    float4 ov; ov.x = v0; ov.y = v1; ov.z = v2; ov.w = v3;
    *(float4*)&out[o0] = ov;

    // publish compensated bf16 state: verified __hip_atomic SYSTEM stores
    unsigned short h0 = f2bf_rn(v0), h1 = f2bf_rn(v1);
    unsigned short h2 = f2bf_rn(v2), h3 = f2bf_rn(v3);
    unsigned short l0 = f2bf_rn(v0 - bf2f(h0)), l1 = f2bf_rn(v1 - bf2f(h1));
    unsigned short l2 = f2bf_rn(v2 - bf2f(h2)), l3 = f2bf_rn(v3 - bf2f(h3));
    unsigned long long hp =
        (unsigned long long)((unsigned int)h0 | ((unsigned int)h1 << 16)) |
        ((unsigned long long)((unsigned int)h2 | ((unsigned int)h3 << 16)) << 32);
    unsigned long long lp =
        (unsigned long long)((unsigned int)l0 | ((unsigned int)l1 << 16)) |
        ((unsigned long long)((unsigned int)l2 | ((unsigned int)l3 << 16)) << 32);
    unsigned long long* dh =
        (unsigned long long*)(st_hi + ncur * (B_ * N_) + (size_t)rm * N_ + colg);
    unsigned long long* dl =
        (unsigned long long*)(st_lo + ncur * (B_ * N_) + (size_t)rm * N_ + colg);
    __hip_atomic_store(dh, hp, __ATOMIC_RELAXED, __HIP_MEMORY_SCOPE_SYSTEM);
    __hip_atomic_store(dl, lp, __ATOMIC_RELAXED, __HIP_MEMORY_SCOPE_SYSTEM);

    // drain, block barrier (restores the all-32 step guarantee -> WAR safe),
    // tid0 posts block flag (verified form)
    asm volatile("s_waitcnt vmcnt(0)" ::: "memory");
    __syncthreads();
    if (tid == 0) {
      __hip_atomic_store(&flags[blk * 16], t, __ATOMIC_RELAXED,
                         __HIP_MEMORY_SCOPE_SYSTEM);
    }
  }
}

// ---------------------------------------------------------------------------
extern "C" void kernel_launch(void* const* d_in, const int* in_sizes, int n_in,
                              void* d_out, int out_size, void* d_ws, size_t ws_size,
                              hipStream_t stream) {
  const float* x       = (const float*)d_in[0];
  const float* w_in    = (const float*)d_in[1];
  const float* w_res   = (const float*)d_in[2];
  const float* wscale  = (const float*)d_in[3];
  const float* states0 = (const float*)d_in[4];
  const float* step0   = (const float*)d_in[5];
  const float* rnoise  = (const float*)d_in[6];
  float* out = (float*)d_out;

  char* ws = (char*)d_ws;
  unsigned short* st_hi = (unsigned short*)ws;                 // 131072 B
  unsigned short* st_lo = (unsigned short*)(ws + 131072);      // 131072 B
  int* flags            = (int*)(ws + 262144);                 // 4096 B

  xin_gemm<<<dim3(256, 16), 256, 0, stream>>>(x, w_in, wscale, out);
  init_k<<<128, 256, 0, stream>>>(states0, step0, out, st_hi, st_lo, flags);
  esn_rec<<<NWORK, 256, 0, stream>>>(w_res, rnoise, out, st_hi, st_lo, flags);
}